// Round 7
// baseline (132.710 us; speedup 1.0000x reference)
//
#include <hip/hip_runtime.h>

// EmbeddingBag sum: out[b, :] = sum_{j<BAG} weight[input[b,j], :]
// input: int32 [BATCH, BAG], weight: fp32 [NUM_EMB+1, EMB_DIM], out: fp32 [BATCH, EMB_DIM]
//
// Forced-MLP: one row per 64-lane wave (lane holds float2 = 512B/row).
// All 50 gathers issue into a register array, then sched_barrier(0) pins the
// schedule so the compiler CANNOT sink the adds between the loads (round-5
// failure mode: VGPR=48 proved it re-fused the loops, window ~16 loads).
// Uniform row id -> indices in SGPRs; gather = saddr-form global_load_dwordx2
// (scalar base per load + one shared lane-voffset VGPR).

constexpr int BATCH = 16384;
constexpr int BAG = 50;
constexpr int DIM = 128;
constexpr int WAVES_PER_BLOCK = 4;
constexpr int BLOCK = 64 * WAVES_PER_BLOCK;

__global__ __launch_bounds__(BLOCK, 2) void embbag_sum_kernel(
    const int* __restrict__ idx,
    const float* __restrict__ weight,
    float* __restrict__ out) {
    const int lane = threadIdx.x & 63;
    const int row = __builtin_amdgcn_readfirstlane(
        blockIdx.x * WAVES_PER_BLOCK + (threadIdx.x >> 6));

    const int* __restrict__ ip = idx + (size_t)row * BAG;

    // Wave-uniform -> scalar s_loads into SGPRs
    int ids[BAG];
#pragma unroll
    for (int j = 0; j < BAG; ++j) ids[j] = ip[j];

    // Issue ALL 50 gathers back-to-back; nothing may be scheduled in between.
    float2 v[BAG];
#pragma unroll
    for (int j = 0; j < BAG; ++j) {
        v[j] = reinterpret_cast<const float2*>(
            weight + ((size_t)ids[j] << 7))[lane];
    }
    // Fence: forbid the scheduler from sinking the adds above into the load
    // stream (which would shrink the in-flight window back to ~16).
    __builtin_amdgcn_sched_barrier(0);

    // Pairwise tree reduce (short dep chain)
    float2 s[BAG / 2 + 1];
#pragma unroll
    for (int j = 0; j < BAG / 2; ++j) {
        s[j].x = v[2 * j].x + v[2 * j + 1].x;
        s[j].y = v[2 * j].y + v[2 * j + 1].y;
    }
    s[BAG / 2] = v[BAG - 1];  // 50 is even -> 25 exact pairs; guard below anyway
    float2 acc = make_float2(0.f, 0.f);
#pragma unroll
    for (int j = 0; j < BAG / 2; ++j) {
        acc.x += s[j].x;
        acc.y += s[j].y;
    }
    if (BAG & 1) {
        acc.x += v[BAG - 1].x;
        acc.y += v[BAG - 1].y;
    }

    *reinterpret_cast<float2*>(out + (size_t)row * DIM + lane * 2) = acc;
}

extern "C" void kernel_launch(void* const* d_in, const int* in_sizes, int n_in,
                              void* d_out, int out_size, void* d_ws, size_t ws_size,
                              hipStream_t stream) {
    const int* idx = (const int*)d_in[0];        // [BATCH, BAG] int32
    const float* weight = (const float*)d_in[1]; // [NUM_EMB+1, DIM] fp32
    float* out = (float*)d_out;                  // [BATCH, DIM] fp32

    const int grid = BATCH / WAVES_PER_BLOCK;    // 4096 blocks
    embbag_sum_kernel<<<grid, BLOCK, 0, stream>>>(idx, weight, out);
}

// Round 8
// 116.592 us; speedup vs baseline: 1.1382x; 1.1382x over previous
//
#include <hip/hip_runtime.h>

// EmbeddingBag sum: out[b, :] = sum_{j<BAG} weight[input[b,j], :]
// input: int32 [BATCH, BAG], weight: fp32 [NUM_EMB+1, EMB_DIM], out: fp32 [BATCH, EMB_DIM]
//
// Round 8 probe: bytes-vs-transactions. Rounds 2/3/5/7 (three structures) all
// pin at ~58us / 3.4 TB/s beyond-L2 random-512B gather -> service-rate bound.
// Halve gathered bytes: pass 1 converts the table to bf16 in d_ws (RNE),
// pass 2 gathers 256B/row (one dword per lane). If bytes-bound, gather time
// halves; if transaction-bound, unchanged -> roofline.

constexpr int BATCH = 16384;
constexpr int BAG = 50;
constexpr int DIM = 128;
constexpr int NROWS = 100001;                       // NUM_EMB + 1
constexpr size_t TAB_ELEMS = (size_t)NROWS * DIM;   // 12,800,128 (div by 4)
constexpr int WAVES_PER_BLOCK = 4;
constexpr int BLOCK = 64 * WAVES_PER_BLOCK;

// ---- pass 1: fp32 -> bf16 (round-to-nearest-even) streaming conversion ----
__global__ __launch_bounds__(256) void cvt_bf16_kernel(
    const float* __restrict__ w, unsigned short* __restrict__ wb) {
    const size_t i0 = ((size_t)blockIdx.x * 256 + threadIdx.x) * 4;
    const size_t stride = (size_t)gridDim.x * 256 * 4;
    for (size_t i = i0; i < TAB_ELEMS; i += stride) {
        const float4 v = *reinterpret_cast<const float4*>(w + i);
        ushort4 o;
        const float f[4] = {v.x, v.y, v.z, v.w};
        unsigned short r[4];
#pragma unroll
        for (int k = 0; k < 4; ++k) {
            unsigned u = __float_as_uint(f[k]);
            u += 0x7FFFu + ((u >> 16) & 1u);        // RNE
            r[k] = (unsigned short)(u >> 16);
        }
        o.x = r[0]; o.y = r[1]; o.z = r[2]; o.w = r[3];
        *reinterpret_cast<ushort4*>(wb + i) = o;
    }
}

// ---- pass 2: gather-sum from bf16 table, one row per 64-lane wave ----
__global__ __launch_bounds__(BLOCK) void embbag_sum_bf16_kernel(
    const int* __restrict__ idx,
    const unsigned int* __restrict__ wb,   // bf16 table viewed as u32 pairs
    float* __restrict__ out) {
    const int lane = threadIdx.x & 63;
    const int row = __builtin_amdgcn_readfirstlane(
        blockIdx.x * WAVES_PER_BLOCK + (threadIdx.x >> 6));

    const int* __restrict__ ip = idx + (size_t)row * BAG;
    int ids[BAG];
#pragma unroll
    for (int j = 0; j < BAG; ++j) ids[j] = ip[j];

    float accx = 0.f, accy = 0.f;
#pragma unroll
    for (int j = 0; j < BAG; ++j) {
        // row = 128 bf16 = 64 u32; lane owns u32 #lane (elems 2*lane, 2*lane+1)
        const unsigned u = wb[((size_t)ids[j] << 6) + lane];
        accx += __uint_as_float(u << 16);
        accy += __uint_as_float(u & 0xFFFF0000u);
    }

    float2 acc = make_float2(accx, accy);
    *reinterpret_cast<float2*>(out + (size_t)row * DIM + lane * 2) = acc;
}

// ---- fallback: proven fp32 path (round 3/5 structure, ~58us) ----
__global__ __launch_bounds__(BLOCK) void embbag_sum_f32_kernel(
    const int* __restrict__ idx,
    const float* __restrict__ weight,
    float* __restrict__ out) {
    const int lane = threadIdx.x & 63;
    const int row = __builtin_amdgcn_readfirstlane(
        blockIdx.x * WAVES_PER_BLOCK + (threadIdx.x >> 6));

    const int* __restrict__ ip = idx + (size_t)row * BAG;
    int ids[BAG];
#pragma unroll
    for (int j = 0; j < BAG; ++j) ids[j] = ip[j];

    float2 acc = make_float2(0.f, 0.f);
#pragma unroll
    for (int j = 0; j < BAG; ++j) {
        const float2 v = reinterpret_cast<const float2*>(
            weight + ((size_t)ids[j] << 7))[lane];
        acc.x += v.x;
        acc.y += v.y;
    }
    *reinterpret_cast<float2*>(out + (size_t)row * DIM + lane * 2) = acc;
}

extern "C" void kernel_launch(void* const* d_in, const int* in_sizes, int n_in,
                              void* d_out, int out_size, void* d_ws, size_t ws_size,
                              hipStream_t stream) {
    const int* idx = (const int*)d_in[0];        // [BATCH, BAG] int32
    const float* weight = (const float*)d_in[1]; // [NROWS, DIM] fp32
    float* out = (float*)d_out;                  // [BATCH, DIM] fp32

    const size_t need = TAB_ELEMS * sizeof(unsigned short);  // ~25.6 MB
    const int grid = BATCH / WAVES_PER_BLOCK;                // 4096 blocks

    if (ws_size >= need) {
        unsigned short* wb = (unsigned short*)d_ws;
        cvt_bf16_kernel<<<2048, 256, 0, stream>>>(weight, wb);
        embbag_sum_bf16_kernel<<<grid, BLOCK, 0, stream>>>(
            idx, (const unsigned int*)wb, out);
    } else {
        embbag_sum_f32_kernel<<<grid, BLOCK, 0, stream>>>(idx, weight, out);
    }
}